// Round 17
// baseline (286.912 us; speedup 1.0000x reference)
//
#include <hip/hip_runtime.h>

// DiceLoss: loss1 = 2*sum((inp>0.5)*tgt); loss2 = sum(inp>0.5) + sum(tgt)
// Round 15-17: split-phase discriminator. Dual-stream read-reduce is pinned at
// ~2.6 TB/s regardless of block count / occupancy / ILP / residency
// (R2/R8/R9/R14). Test whether SINGLE-stream phases stream faster:
//   A: read inp -> bitmask (1b/elem, 4 MiB) + per-block bin counts
//   B: read tgt + mask -> per-block inter/tgt partials
//   C: reduce 3x2048 partials -> out[0..1]. No atomics anywhere.

#define T1 256
#define BLK_E 16384LL   // elements per block in phases A/B (2048 blocks at n=32M)

__global__ __launch_bounds__(T1) void dice_mask_kernel(
    const float* __restrict__ inp, unsigned char* __restrict__ mask,
    float* __restrict__ pbin, long long n)
{
    const float4* __restrict__ in4 = (const float4*)inp;
    const int wave = threadIdx.x >> 6;
    const int lane = threadIdx.x & 63;
    // wave owns 4096 consecutive elements; lane owns 8 consecutive per iter
    const long long wv_e = (long long)blockIdx.x * BLK_E + (long long)wave * 4096;

    float s_bin = 0.f;

    if (wv_e + 4096 <= n) {
        const long long f4 = (wv_e >> 2) + (long long)lane * 2;  // float4 idx
        const long long mb = (wv_e >> 3) + lane;                 // mask byte idx
        #pragma unroll
        for (int k = 0; k < 8; ++k) {
            float4 a0 = in4[f4 + k * 128];
            float4 a1 = in4[f4 + k * 128 + 1];
            unsigned m = (a0.x > 0.5f ? 1u   : 0u) | (a0.y > 0.5f ? 2u   : 0u)
                       | (a0.z > 0.5f ? 4u   : 0u) | (a0.w > 0.5f ? 8u   : 0u)
                       | (a1.x > 0.5f ? 16u  : 0u) | (a1.y > 0.5f ? 32u  : 0u)
                       | (a1.z > 0.5f ? 64u  : 0u) | (a1.w > 0.5f ? 128u : 0u);
            mask[mb + (long long)k * 64] = (unsigned char)m;
            s_bin += (float)__popc(m);
        }
    } else {
        // generic tail (not taken at benched shape)
        for (int k = 0; k < 8; ++k) {
            long long e0 = wv_e + (long long)k * 512 + (long long)lane * 8;
            if (e0 < n) {
                unsigned m = 0;
                for (int j = 0; j < 8; ++j) {
                    long long e = e0 + j;
                    if (e < n && inp[e] > 0.5f) m |= (1u << j);
                }
                mask[e0 >> 3] = (unsigned char)m;
                s_bin += (float)__popc(m);
            }
        }
    }

    #pragma unroll
    for (int off = 32; off > 0; off >>= 1) s_bin += __shfl_down(s_bin, off, 64);
    __shared__ float red[4];
    if (lane == 0) red[wave] = s_bin;
    __syncthreads();
    if (threadIdx.x == 0)
        pbin[blockIdx.x] = (red[0] + red[1]) + (red[2] + red[3]);
}

__global__ __launch_bounds__(T1) void dice_tgt_kernel(
    const float* __restrict__ tgt, const unsigned char* __restrict__ mask,
    float* __restrict__ pint, float* __restrict__ ptgt, long long n)
{
    const float4* __restrict__ tg4 = (const float4*)tgt;
    const int wave = threadIdx.x >> 6;
    const int lane = threadIdx.x & 63;
    const long long wv_e = (long long)blockIdx.x * BLK_E + (long long)wave * 4096;

    float s_inter = 0.f, s_tgt = 0.f;

    if (wv_e + 4096 <= n) {
        const long long f4 = (wv_e >> 2) + (long long)lane * 2;
        const long long mb = (wv_e >> 3) + lane;
        #pragma unroll
        for (int k = 0; k < 8; ++k) {
            float4 b0 = tg4[f4 + k * 128];
            float4 b1 = tg4[f4 + k * 128 + 1];
            unsigned m = mask[mb + (long long)k * 64];
            s_tgt   += (b0.x + b0.y) + (b0.z + b0.w)
                     + (b1.x + b1.y) + (b1.z + b1.w);
            s_inter += ((m & 1u   ? b0.x : 0.f) + (m & 2u   ? b0.y : 0.f))
                     + ((m & 4u   ? b0.z : 0.f) + (m & 8u   ? b0.w : 0.f))
                     + ((m & 16u  ? b1.x : 0.f) + (m & 32u  ? b1.y : 0.f))
                     + ((m & 64u  ? b1.z : 0.f) + (m & 128u ? b1.w : 0.f));
        }
    } else {
        // generic tail (not taken at benched shape)
        for (int k = 0; k < 8; ++k) {
            long long e0 = wv_e + (long long)k * 512 + (long long)lane * 8;
            if (e0 < n) {
                unsigned m = mask[e0 >> 3];
                for (int j = 0; j < 8; ++j) {
                    long long e = e0 + j;
                    if (e < n) {
                        float v = tgt[e];
                        s_tgt += v;
                        if (m & (1u << j)) s_inter += v;
                    }
                }
            }
        }
    }

    #pragma unroll
    for (int off = 32; off > 0; off >>= 1) {
        s_inter += __shfl_down(s_inter, off, 64);
        s_tgt   += __shfl_down(s_tgt,   off, 64);
    }
    __shared__ float red[2][4];
    if (lane == 0) { red[0][wave] = s_inter; red[1][wave] = s_tgt; }
    __syncthreads();
    if (threadIdx.x == 0) {
        pint[blockIdx.x] = (red[0][0] + red[0][1]) + (red[0][2] + red[0][3]);
        ptgt[blockIdx.x] = (red[1][0] + red[1][1]) + (red[1][2] + red[1][3]);
    }
}

__global__ __launch_bounds__(T1) void dice_final_kernel(
    const float* __restrict__ pp, float* __restrict__ out, int P)
{
    // pp layout: [0,P) = bin, [P,2P) = inter, [2P,3P) = tgt
    float s_bin = 0.f, s_int = 0.f, s_tgt = 0.f;
    for (int i = threadIdx.x; i < P; i += T1) {
        s_bin += pp[i];
        s_int += pp[P + i];
        s_tgt += pp[2 * P + i];
    }
    #pragma unroll
    for (int off = 32; off > 0; off >>= 1) {
        s_bin += __shfl_down(s_bin, off, 64);
        s_int += __shfl_down(s_int, off, 64);
        s_tgt += __shfl_down(s_tgt, off, 64);
    }
    __shared__ float red[3][4];
    int wave = threadIdx.x >> 6;
    int lane = threadIdx.x & 63;
    if (lane == 0) { red[0][wave] = s_bin; red[1][wave] = s_int; red[2][wave] = s_tgt; }
    __syncthreads();
    if (threadIdx.x == 0) {
        float tb = (red[0][0] + red[0][1]) + (red[0][2] + red[0][3]);
        float ti = (red[1][0] + red[1][1]) + (red[1][2] + red[1][3]);
        float tt = (red[2][0] + red[2][1]) + (red[2][2] + red[2][3]);
        out[0] = 2.f * ti;      // loss1
        out[1] = tb + tt;       // loss2
    }
}

extern "C" void kernel_launch(void* const* d_in, const int* in_sizes, int n_in,
                              void* d_out, int out_size, void* d_ws, size_t ws_size,
                              hipStream_t stream) {
    const float* inp = (const float*)d_in[0];
    const float* tgt = (const float*)d_in[1];
    float* out = (float*)d_out;

    long long n = (long long)in_sizes[0];            // 33,554,432
    unsigned char* mask = (unsigned char*)d_ws;      // n/8 = 4 MiB
    long long mask_bytes = (n + 7) >> 3;
    float* pp = (float*)((char*)d_ws + ((mask_bytes + 255) & ~255LL));

    const int grid1 = (int)((n + BLK_E - 1) / BLK_E);   // 2048 at benched shape

    dice_mask_kernel<<<grid1, T1, 0, stream>>>(inp, mask, pp, n);
    dice_tgt_kernel<<<grid1, T1, 0, stream>>>(tgt, mask, pp + grid1, pp + 2 * grid1, n);
    dice_final_kernel<<<1, T1, 0, stream>>>(pp, out, grid1);
}